// Round 9
// baseline (454.509 us; speedup 1.0000x reference)
//
#include <hip/hip_runtime.h>
#include <hip/hip_fp16.h>
#include <stdint.h>
#include <stddef.h>

typedef _Float16 f16;
typedef _Float16 f16x8 __attribute__((ext_vector_type(8)));
typedef _Float16 f16x4 __attribute__((ext_vector_type(4)));
typedef float    f32x4 __attribute__((ext_vector_type(4)));

#define NB  2
#define NS  2048
#define NDM 1024
#define NH  16
#define ND  64
#define NM  4096   // NB*NS

// ---------------------------------------------------------------------------
// K0a: convert Q/K/V inputs f32 -> f16   (grid: (2048, 3), block 256; 8 elem/thr)
// ---------------------------------------------------------------------------
__global__ __launch_bounds__(256) void cvt_x_kernel(const float* __restrict__ q,
                                                    const float* __restrict__ k,
                                                    const float* __restrict__ v,
                                                    f16* __restrict__ xh)
{
    const float* src = (blockIdx.y == 0) ? q : (blockIdx.y == 1) ? k : v;
    f16* dst = xh + (size_t)blockIdx.y * ((size_t)NM * NDM);
    size_t i = ((size_t)blockIdx.x * 256 + threadIdx.x) * 8;
    float4 a = *(const float4*)(src + i);
    float4 b = *(const float4*)(src + i + 4);
    f16x8 o;
    o[0] = (f16)a.x; o[1] = (f16)a.y; o[2] = (f16)a.z; o[3] = (f16)a.w;
    o[4] = (f16)b.x; o[5] = (f16)b.y; o[6] = (f16)b.z; o[7] = (f16)b.w;
    *(f16x8*)(dst + i) = o;
}

// ---------------------------------------------------------------------------
// K0b: W [K][N] f32 -> Wt [N][K] f16 (transposed, so GEMM B-frags are contiguous)
// grid: (16,16,4), block 256, 64x64 tiles
// ---------------------------------------------------------------------------
__global__ __launch_bounds__(256) void transp_w_kernel(const float* __restrict__ w0,
                                                       const float* __restrict__ w1,
                                                       const float* __restrict__ w2,
                                                       const float* __restrict__ w3,
                                                       f16* __restrict__ wt)
{
    __shared__ float t[64][65];
    const int z = blockIdx.z;
    const float* src = (z==0)?w0:(z==1)?w1:(z==2)?w2:w3;
    f16* dst = wt + (size_t)z * ((size_t)NDM * NDM);
    const int k0 = blockIdx.y * 64, n0 = blockIdx.x * 64;
    const int c = threadIdx.x & 63, r4 = threadIdx.x >> 6;
    #pragma unroll
    for (int i = 0; i < 16; ++i) {
        int r = i*4 + r4;
        t[r][c] = src[(size_t)(k0 + r) * NDM + n0 + c];
    }
    __syncthreads();
    #pragma unroll
    for (int i = 0; i < 16; ++i) {
        int n = i*4 + r4;
        dst[(size_t)(n0 + n) * NDM + k0 + c] = (f16)t[c][n];
    }
}

// ---------------------------------------------------------------------------
// Shared 128x128x(K=1024) f16 GEMM core, 256 thr (4 waves, each 64x64),
// BK=32, double-buffered LDS, reg-staged (2-barrier pattern).
// MODE 0: q = (acc+bq)*0.125*log2e -> [B,H,S,D] f16  (exp2 folding for attn)
// MODE 1: k = acc+bk         -> [B,H,S,D] f16
// MODE 2: v = acc+bv         -> [B,H,D,S] f16 (transposed for PV A-operand)
// MODE 3: out = acc+bo       -> [B,S,DM] f32 (d_out)
// ---------------------------------------------------------------------------
template<int MODE>
__device__ __forceinline__ void gemm128(const f16* __restrict__ A,
                                        const f16* __restrict__ Bw,
                                        const float* __restrict__ bias,
                                        void* __restrict__ outp,
                                        f16* __restrict__ AsB, f16* __restrict__ BsB)
{
    const int tid  = threadIdx.x;
    const int lane = tid & 63;
    const int wid  = tid >> 6;
    const int wr = wid >> 1, wc = wid & 1;
    const int m0 = blockIdx.y * 128, n0 = blockIdx.x * 128;
    const int K = 1024;

    // staging: thread covers 16B chunks {tid, tid+256}; row = c>>2, sub = (c&3)*8
    const int r0 = tid >> 2;
    const int s0 = (tid & 3) * 8;
    const f16* Arow0 = A  + (size_t)(m0 + r0)      * K + s0;
    const f16* Arow1 = A  + (size_t)(m0 + r0 + 64) * K + s0;
    const f16* Brow0 = Bw + (size_t)(n0 + r0)      * K + s0;
    const f16* Brow1 = Bw + (size_t)(n0 + r0 + 64) * K + s0;
    const int lds0 = r0*32 + s0;
    const int lds1 = (r0+64)*32 + s0;

    f16x8 ra0 = *(const f16x8*)(Arow0);
    f16x8 ra1 = *(const f16x8*)(Arow1);
    f16x8 rb0 = *(const f16x8*)(Brow0);
    f16x8 rb1 = *(const f16x8*)(Brow1);
    *(f16x8*)(AsB + lds0) = ra0; *(f16x8*)(AsB + lds1) = ra1;
    *(f16x8*)(BsB + lds0) = rb0; *(f16x8*)(BsB + lds1) = rb1;

    f32x4 acc[4][4];
    #pragma unroll
    for (int i = 0; i < 4; ++i)
        #pragma unroll
        for (int j = 0; j < 4; ++j) {
            f32x4 z4 = {0.f, 0.f, 0.f, 0.f};
            acc[i][j] = z4;
        }

    const int arow = wr*64 + (lane & 15);
    const int brow = wc*64 + (lane & 15);
    const int kc   = (lane >> 4) * 8;

    int cur = 0;
    for (int s = 0; s < 32; ++s) {
        const bool more = (s + 1 < 32);
        if (more) {   // issue next-tile global loads early; latency hides under MFMA
            const int kk = (s + 1) * 32;
            ra0 = *(const f16x8*)(Arow0 + kk); ra1 = *(const f16x8*)(Arow1 + kk);
            rb0 = *(const f16x8*)(Brow0 + kk); rb1 = *(const f16x8*)(Brow1 + kk);
        }
        __syncthreads();   // buf[cur] ds_writes visible
        {
            f16x8 af[4], bf[4];
            f16* Asc = AsB + cur*4096;
            f16* Bsc = BsB + cur*4096;
            #pragma unroll
            for (int rt = 0; rt < 4; ++rt) af[rt] = *(const f16x8*)(Asc + (arow + rt*16)*32 + kc);
            #pragma unroll
            for (int ct = 0; ct < 4; ++ct) bf[ct] = *(const f16x8*)(Bsc + (brow + ct*16)*32 + kc);
            #pragma unroll
            for (int rt = 0; rt < 4; ++rt)
                #pragma unroll
                for (int ct = 0; ct < 4; ++ct)
                    acc[rt][ct] = __builtin_amdgcn_mfma_f32_16x16x32_f16(af[rt], bf[ct], acc[rt][ct], 0, 0, 0);
        }
        __syncthreads();   // all reads of buf[cur^1] from prev iter done
        if (more) {
            f16* Asn = AsB + (cur^1)*4096;
            f16* Bsn = BsB + (cur^1)*4096;
            *(f16x8*)(Asn + lds0) = ra0; *(f16x8*)(Asn + lds1) = ra1;
            *(f16x8*)(Bsn + lds0) = rb0; *(f16x8*)(Bsn + lds1) = rb1;
        }
        cur ^= 1;
    }

    // epilogue: C[m][n], m = mb+j (row = (lane>>4)*4+j), n = tile base + (lane&15)
    #pragma unroll
    for (int rt = 0; rt < 4; ++rt) {
        const int mb = m0 + wr*64 + rt*16 + ((lane >> 4) << 2);
        #pragma unroll
        for (int ct = 0; ct < 4; ++ct) {
            const int n = n0 + wc*64 + ct*16 + (lane & 15);
            const float bn = bias[n];
            if (MODE == 0 || MODE == 1) {
                f16* dst = (f16*)outp;
                // MODE 0: fold 1/sqrt(D) AND log2(e) so attn can use exp2 directly
                const float sc = (MODE == 0) ? 0.125f * 1.44269504088896f : 1.0f;
                #pragma unroll
                for (int j = 0; j < 4; ++j) {
                    const int m = mb + j;
                    const float v = (acc[rt][ct][j] + bn) * sc;
                    // [B,H,S,D]: ((b*16+h)*2048+s)*64+d
                    dst[(size_t)((m >> 11)*16 + (n >> 6))*131072 + (size_t)(m & 2047)*64 + (n & 63)] = (f16)v;
                }
            } else if (MODE == 2) {
                f16* dst = (f16*)outp;
                f16x4 o;
                #pragma unroll
                for (int j = 0; j < 4; ++j) o[j] = (f16)(acc[rt][ct][j] + bn);
                // [B,H,D,S]: ((b*16+h)*64+d)*2048+s ; 4 consecutive s -> 8B store
                *(f16x4*)(dst + (size_t)((mb >> 11)*16 + (n >> 6))*131072 + (size_t)(n & 63)*2048 + (mb & 2047)) = o;
            } else {
                float* dst = (float*)outp;
                #pragma unroll
                for (int j = 0; j < 4; ++j) {
                    const int m = mb + j;
                    dst[(size_t)m * NDM + n] = acc[rt][ct][j] + bn;
                }
            }
        }
    }
}

// fused QKV projection: grid (8, 32, 3)
__global__ __launch_bounds__(256) void proj_kernel(const f16* __restrict__ xh, const f16* __restrict__ wt,
                                                   const float* __restrict__ bq, const float* __restrict__ bk,
                                                   const float* __restrict__ bv,
                                                   f16* __restrict__ qh, f16* __restrict__ kh, f16* __restrict__ vh)
{
    __shared__ f16 AsS[2*4096];
    __shared__ f16 BsS[2*4096];
    const int z = blockIdx.z;
    const f16* A  = xh + (size_t)z * ((size_t)NM * NDM);
    const f16* Bw = wt + (size_t)z * ((size_t)NDM * NDM);
    if (z == 0)      gemm128<0>(A, Bw, bq, qh, AsS, BsS);
    else if (z == 1) gemm128<1>(A, Bw, bk, kh, AsS, BsS);
    else             gemm128<2>(A, Bw, bv, vh, AsS, BsS);
}

// output projection: grid (8, 32)
__global__ __launch_bounds__(256) void outproj_kernel(const f16* __restrict__ ah, const f16* __restrict__ wto,
                                                      const float* __restrict__ bo, float* __restrict__ out)
{
    __shared__ f16 AsS[2*4096];
    __shared__ f16 BsS[2*4096];
    gemm128<3>(ah, wto, bo, out, AsS, BsS);
}

// ---------------------------------------------------------------------------
// K2: fused attention, P-IN-REGISTERS (no LDS on the QK->write->PV path).
// 1 block = one (b,h) x 16 q-rows; 512 thr (8 waves). Wave wid owns k-columns
// {t*128 + wid*16 + 0..15} for t=0..15.
// Phase 1: swapped mfma(K,Q) 16x16x32; lane (g,l15) gets s[l15][t*128+wid*16+
//   g*4+u] -> exp2 -> f16x4 p16[16] in REGISTERS (fully unrolled, static idx).
//   No ds_write. Rowsum via 2 shfl_xor + 128-float LDS + barrier.
// Phase 2 (all 8 waves): per t, interleave {V prefetch, one nt f32x4 weights
//   store from regs (64B-contiguous per 4-lane group), 4x mfma 16x16x16 PV}.
//   p16 is EXACTLY the 16x16x16 B-fragment (k=g*4+u, col=l15): zero shuffles.
// PV partials (each wave covered 1/8 of k) reduced via padded LDS scratch.
// grid: 4096; XCD swizzle keeps each (b,h)'s 512 KB K/V in one XCD's L2.
// ---------------------------------------------------------------------------
__global__ __launch_bounds__(512) void attn_kernel(const f16* __restrict__ qh, const f16* __restrict__ kh,
                                                   const f16* __restrict__ vt, f16* __restrict__ ah,
                                                   float* __restrict__ wout)
{
    __shared__ __align__(16) float scratch[8][16][68];  // [wave][q][d(+4 pad)] ~34.8 KB
    __shared__ float redbuf[128];
    __shared__ float rinv[16];

    const int tid  = threadIdx.x;
    const int lane = tid & 63;
    const int wid  = tid >> 6;
    const int l15  = lane & 15;
    const int g    = lane >> 4;

    // XCD swizzle: 4 bh per XCD, all 128 q-tile blocks of a bh on one XCD.
    const int xcd   = blockIdx.x & 7;
    const int j     = blockIdx.x >> 3;
    const int bh    = xcd * 4 + (j & 3);
    const int qbase = (j >> 2) * 16;

    const f16* qp = qh + ((size_t)bh * NS + qbase) * 64;
    const f16* kp = kh + (size_t)bh * NS * 64;
    const f16* vp = vt + (size_t)bh * 64 * NS;

    // q fragments (B-operand of QK): col = l15 (q row), depth = g*8+e (+32)
    const f16x8 qf0 = *(const f16x8*)(qp + l15*64 + g*8);
    const f16x8 qf1 = *(const f16x8*)(qp + l15*64 + 32 + g*8);

    // ---- phase 1: QK -> exp2 -> registers; rowsum ----
    float rs = 0.f;
    f16x4 p16[16];
    const f16* kbase = kp + (size_t)(wid*16 + l15) * 64 + g*8;
    #pragma unroll
    for (int t = 0; t < 16; ++t) {
        const f16* kb = kbase + (size_t)t * 8192;   // 128 k-rows * 64
        f16x8 kf0 = *(const f16x8*)(kb);
        f16x8 kf1 = *(const f16x8*)(kb + 32);
        f32x4 a = {0.f, 0.f, 0.f, 0.f};
        a = __builtin_amdgcn_mfma_f32_16x16x32_f16(kf0, qf0, a, 0, 0, 0);
        a = __builtin_amdgcn_mfma_f32_16x16x32_f16(kf1, qf1, a, 0, 0, 0);
        // lane holds s[q=l15][k = t*128 + wid*16 + g*4 + u]
        f16x4 pv_;
        #pragma unroll
        for (int u = 0; u < 4; ++u) {
            float e = __builtin_amdgcn_exp2f(a[u]);
            rs += e;
            pv_[u] = (f16)e;
        }
        p16[t] = pv_;
    }

    rs += __shfl_xor(rs, 16);
    rs += __shfl_xor(rs, 32);
    if (lane < 16) redbuf[wid*16 + lane] = rs;
    __syncthreads();
    if (tid < 16) {
        float sum = 0.f;
        #pragma unroll
        for (int w = 0; w < 8; ++w) sum += redbuf[w*16 + tid];
        rinv[tid] = 1.0f / sum;
    }
    __syncthreads();
    const float ri = rinv[l15];

    // ---- phase 2: weights stores (from regs) interleaved with PV MFMAs ----
    const int kloc = wid*16 + g*4;                      // column within each 128-chunk
    float* wr = wout + ((size_t)bh * NS + qbase + l15) * NS + kloc;
    const f16* vb = vp + (size_t)l15 * NS + kloc;       // V^T row d=dt*16+l15

    f32x4 acc0 = {0.f,0.f,0.f,0.f}, acc1 = acc0, acc2 = acc0, acc3 = acc0;
    f16x4 cV0 = *(const f16x4*)(vb);
    f16x4 cV1 = *(const f16x4*)(vb + 16*NS);
    f16x4 cV2 = *(const f16x4*)(vb + 32*NS);
    f16x4 cV3 = *(const f16x4*)(vb + 48*NS);

    #pragma unroll
    for (int t = 0; t < 16; ++t) {
        const int tn = (t + 1) & 15;    // last prefetch wraps (in-bounds, unused)
        const f16* vn = vb + tn*128;
        f16x4 nV0 = *(const f16x4*)(vn);
        f16x4 nV1 = *(const f16x4*)(vn + 16*NS);
        f16x4 nV2 = *(const f16x4*)(vn + 32*NS);
        f16x4 nV3 = *(const f16x4*)(vn + 48*NS);

        // normalized weights from registers (issued after loads -> loads retire first)
        f32x4 w;
        #pragma unroll
        for (int u = 0; u < 4; ++u) w[u] = (float)p16[t][u] * ri;
        __builtin_nontemporal_store(w, (f32x4*)(wr + t*128));

        // PV: A = V^T (row=d_local l15... per-dt), B = p16[t] (k=g*4+u, col=l15)
        acc0 = __builtin_amdgcn_mfma_f32_16x16x16f16(cV0, p16[t], acc0, 0, 0, 0);
        acc1 = __builtin_amdgcn_mfma_f32_16x16x16f16(cV1, p16[t], acc1, 0, 0, 0);
        acc2 = __builtin_amdgcn_mfma_f32_16x16x16f16(cV2, p16[t], acc2, 0, 0, 0);
        acc3 = __builtin_amdgcn_mfma_f32_16x16x16f16(cV3, p16[t], acc3, 0, 0, 0);

        cV0 = nV0; cV1 = nV1; cV2 = nV2; cV3 = nV3;
    }

    // partials -> LDS: D[row=g*4+u][col=l15] = PV[d=dt*16+g*4+u][q=l15]
    {
        float* sc = &scratch[wid][l15][g*4];
        *(f32x4*)(sc)      = acc0;
        *(f32x4*)(sc + 16) = acc1;
        *(f32x4*)(sc + 32) = acc2;
        *(f32x4*)(sc + 48) = acc3;
    }
    __syncthreads();

    // cross-wave reduce (8 partials), normalize, store ah [B,S,DM] f16
    {
        const int bb = bh >> 4, hh = bh & 15;
        #pragma unroll
        for (int r = 0; r < 2; ++r) {
            const int idx = tid + r*512;          // 0..1023 over [q][d]
            const int q = idx >> 6, d = idx & 63;
            float s = 0.f;
            #pragma unroll
            for (int w2 = 0; w2 < 8; ++w2) s += scratch[w2][q][d];
            ah[((size_t)(bb*NS + qbase + q)) * NDM + hh*64 + d] = (f16)(s * rinv[q]);
        }
    }
}

// ---------------------------------------------------------------------------
extern "C" void kernel_launch(void* const* d_in, const int* in_sizes, int n_in,
                              void* d_out, int out_size, void* d_ws, size_t ws_size,
                              hipStream_t stream)
{
    (void)in_sizes; (void)n_in; (void)out_size;
    const float* Q  = (const float*)d_in[0];
    const float* K  = (const float*)d_in[1];
    const float* V  = (const float*)d_in[2];
    const float* Wq = (const float*)d_in[3];
    const float* bq = (const float*)d_in[4];
    const float* Wk = (const float*)d_in[5];
    const float* bk = (const float*)d_in[6];
    const float* Wv = (const float*)d_in[7];
    const float* bv = (const float*)d_in[8];
    const float* Wo = (const float*)d_in[9];
    const float* bo = (const float*)d_in[10];

    if (ws_size < 67108864ull) return;  // need 64 MiB; abort -> stub-like absmax signals this

    f16* ws = (f16*)d_ws;
    f16* Xh = ws;                  // 3 x [4096][1024] f16 (Q,K,V inputs)
    f16* Wt = ws + 12582912;       // 4 x [1024][1024] f16 (W^T: q,k,v,o)
    f16* qh = ws + 16777216;       // [B,H,S,D] f16, pre-scaled by 0.125*log2e
    f16* kh = ws + 20971520;       // [B,H,S,D] f16
    f16* vt = ws + 25165824;       // [B,H,D,S] f16 (transposed)
    f16* ah = ws + 29360128;       // [B,S,DM] f16 (attn concat)
    float* out  = (float*)d_out;
    float* wout = out + 4194304;   // weights region

    cvt_x_kernel  <<<dim3(2048, 3, 1), dim3(256), 0, stream>>>(Q, K, V, Xh);
    transp_w_kernel<<<dim3(16, 16, 4), dim3(256), 0, stream>>>(Wq, Wk, Wv, Wo, Wt);
    proj_kernel   <<<dim3(8, 32, 3),  dim3(256), 0, stream>>>(Xh, Wt, bq, bk, bv, qh, kh, vt);
    attn_kernel   <<<dim3(4096),      dim3(512), 0, stream>>>(qh, kh, vt, ah, wout);
    outproj_kernel<<<dim3(8, 32, 1),  dim3(256), 0, stream>>>(ah, Wt + 3*1048576, bo, out);
}

// Round 10
// 357.117 us; speedup vs baseline: 1.2727x; 1.2727x over previous
//
#include <hip/hip_runtime.h>
#include <hip/hip_fp16.h>
#include <stdint.h>
#include <stddef.h>

typedef _Float16 f16;
typedef _Float16 f16x8 __attribute__((ext_vector_type(8)));
typedef _Float16 f16x4 __attribute__((ext_vector_type(4)));
typedef float    f32x4 __attribute__((ext_vector_type(4)));

#define NB  2
#define NS  2048
#define NDM 1024
#define NH  16
#define ND  64
#define NM  4096   // NB*NS

// ---------------------------------------------------------------------------
// K0a: convert Q/K/V inputs f32 -> f16   (grid: (2048, 3), block 256; 8 elem/thr)
// ---------------------------------------------------------------------------
__global__ __launch_bounds__(256) void cvt_x_kernel(const float* __restrict__ q,
                                                    const float* __restrict__ k,
                                                    const float* __restrict__ v,
                                                    f16* __restrict__ xh)
{
    const float* src = (blockIdx.y == 0) ? q : (blockIdx.y == 1) ? k : v;
    f16* dst = xh + (size_t)blockIdx.y * ((size_t)NM * NDM);
    size_t i = ((size_t)blockIdx.x * 256 + threadIdx.x) * 8;
    float4 a = *(const float4*)(src + i);
    float4 b = *(const float4*)(src + i + 4);
    f16x8 o;
    o[0] = (f16)a.x; o[1] = (f16)a.y; o[2] = (f16)a.z; o[3] = (f16)a.w;
    o[4] = (f16)b.x; o[5] = (f16)b.y; o[6] = (f16)b.z; o[7] = (f16)b.w;
    *(f16x8*)(dst + i) = o;
}

// ---------------------------------------------------------------------------
// K0b: W [K][N] f32 -> Wt [N][K] f16 (transposed, so GEMM B-frags are contiguous)
// grid: (16,16,4), block 256, 64x64 tiles
// ---------------------------------------------------------------------------
__global__ __launch_bounds__(256) void transp_w_kernel(const float* __restrict__ w0,
                                                       const float* __restrict__ w1,
                                                       const float* __restrict__ w2,
                                                       const float* __restrict__ w3,
                                                       f16* __restrict__ wt)
{
    __shared__ float t[64][65];
    const int z = blockIdx.z;
    const float* src = (z==0)?w0:(z==1)?w1:(z==2)?w2:w3;
    f16* dst = wt + (size_t)z * ((size_t)NDM * NDM);
    const int k0 = blockIdx.y * 64, n0 = blockIdx.x * 64;
    const int c = threadIdx.x & 63, r4 = threadIdx.x >> 6;
    #pragma unroll
    for (int i = 0; i < 16; ++i) {
        int r = i*4 + r4;
        t[r][c] = src[(size_t)(k0 + r) * NDM + n0 + c];
    }
    __syncthreads();
    #pragma unroll
    for (int i = 0; i < 16; ++i) {
        int n = i*4 + r4;
        dst[(size_t)(n0 + n) * NDM + k0 + c] = (f16)t[c][n];
    }
}

// ---------------------------------------------------------------------------
// Shared 128x128x(K=1024) f16 GEMM core, 256 thr (4 waves, each 64x64),
// BK=32, double-buffered LDS, reg-staged (2-barrier pattern).
// MODE 0: q = (acc+bq)*0.125*log2e -> [B,H,S,D] f16  (exp2 folding for attn)
// MODE 1: k = acc+bk         -> [B,H,S,D] f16
// MODE 2: v = acc+bv         -> [B,H,D,S] f16 (transposed for PV A-operand)
// MODE 3: out = acc+bo       -> [B,S,DM] f32 (d_out)
// ---------------------------------------------------------------------------
template<int MODE>
__device__ __forceinline__ void gemm128(const f16* __restrict__ A,
                                        const f16* __restrict__ Bw,
                                        const float* __restrict__ bias,
                                        void* __restrict__ outp,
                                        f16* __restrict__ AsB, f16* __restrict__ BsB)
{
    const int tid  = threadIdx.x;
    const int lane = tid & 63;
    const int wid  = tid >> 6;
    const int wr = wid >> 1, wc = wid & 1;
    const int m0 = blockIdx.y * 128, n0 = blockIdx.x * 128;
    const int K = 1024;

    // staging: thread covers 16B chunks {tid, tid+256}; row = c>>2, sub = (c&3)*8
    const int r0 = tid >> 2;
    const int s0 = (tid & 3) * 8;
    const f16* Arow0 = A  + (size_t)(m0 + r0)      * K + s0;
    const f16* Arow1 = A  + (size_t)(m0 + r0 + 64) * K + s0;
    const f16* Brow0 = Bw + (size_t)(n0 + r0)      * K + s0;
    const f16* Brow1 = Bw + (size_t)(n0 + r0 + 64) * K + s0;
    const int lds0 = r0*32 + s0;
    const int lds1 = (r0+64)*32 + s0;

    f16x8 ra0 = *(const f16x8*)(Arow0);
    f16x8 ra1 = *(const f16x8*)(Arow1);
    f16x8 rb0 = *(const f16x8*)(Brow0);
    f16x8 rb1 = *(const f16x8*)(Brow1);
    *(f16x8*)(AsB + lds0) = ra0; *(f16x8*)(AsB + lds1) = ra1;
    *(f16x8*)(BsB + lds0) = rb0; *(f16x8*)(BsB + lds1) = rb1;

    f32x4 acc[4][4];
    #pragma unroll
    for (int i = 0; i < 4; ++i)
        #pragma unroll
        for (int j = 0; j < 4; ++j) {
            f32x4 z4 = {0.f, 0.f, 0.f, 0.f};
            acc[i][j] = z4;
        }

    const int arow = wr*64 + (lane & 15);
    const int brow = wc*64 + (lane & 15);
    const int kc   = (lane >> 4) * 8;

    int cur = 0;
    for (int s = 0; s < 32; ++s) {
        const bool more = (s + 1 < 32);
        if (more) {   // issue next-tile global loads early; latency hides under MFMA
            const int kk = (s + 1) * 32;
            ra0 = *(const f16x8*)(Arow0 + kk); ra1 = *(const f16x8*)(Arow1 + kk);
            rb0 = *(const f16x8*)(Brow0 + kk); rb1 = *(const f16x8*)(Brow1 + kk);
        }
        __syncthreads();   // buf[cur] ds_writes visible
        {
            f16x8 af[4], bf[4];
            f16* Asc = AsB + cur*4096;
            f16* Bsc = BsB + cur*4096;
            #pragma unroll
            for (int rt = 0; rt < 4; ++rt) af[rt] = *(const f16x8*)(Asc + (arow + rt*16)*32 + kc);
            #pragma unroll
            for (int ct = 0; ct < 4; ++ct) bf[ct] = *(const f16x8*)(Bsc + (brow + ct*16)*32 + kc);
            #pragma unroll
            for (int rt = 0; rt < 4; ++rt)
                #pragma unroll
                for (int ct = 0; ct < 4; ++ct)
                    acc[rt][ct] = __builtin_amdgcn_mfma_f32_16x16x32_f16(af[rt], bf[ct], acc[rt][ct], 0, 0, 0);
        }
        __syncthreads();   // all reads of buf[cur^1] from prev iter done
        if (more) {
            f16* Asn = AsB + (cur^1)*4096;
            f16* Bsn = BsB + (cur^1)*4096;
            *(f16x8*)(Asn + lds0) = ra0; *(f16x8*)(Asn + lds1) = ra1;
            *(f16x8*)(Bsn + lds0) = rb0; *(f16x8*)(Bsn + lds1) = rb1;
        }
        cur ^= 1;
    }

    // epilogue: C[m][n], m = mb+j (row = (lane>>4)*4+j), n = tile base + (lane&15)
    #pragma unroll
    for (int rt = 0; rt < 4; ++rt) {
        const int mb = m0 + wr*64 + rt*16 + ((lane >> 4) << 2);
        #pragma unroll
        for (int ct = 0; ct < 4; ++ct) {
            const int n = n0 + wc*64 + ct*16 + (lane & 15);
            const float bn = bias[n];
            if (MODE == 0 || MODE == 1) {
                f16* dst = (f16*)outp;
                // MODE 0: fold 1/sqrt(D) AND log2(e) so attn can use exp2 directly
                const float sc = (MODE == 0) ? 0.125f * 1.44269504088896f : 1.0f;
                #pragma unroll
                for (int j = 0; j < 4; ++j) {
                    const int m = mb + j;
                    const float v = (acc[rt][ct][j] + bn) * sc;
                    // [B,H,S,D]: ((b*16+h)*2048+s)*64+d
                    dst[(size_t)((m >> 11)*16 + (n >> 6))*131072 + (size_t)(m & 2047)*64 + (n & 63)] = (f16)v;
                }
            } else if (MODE == 2) {
                f16* dst = (f16*)outp;
                f16x4 o;
                #pragma unroll
                for (int j = 0; j < 4; ++j) o[j] = (f16)(acc[rt][ct][j] + bn);
                // [B,H,D,S]: ((b*16+h)*64+d)*2048+s ; 4 consecutive s -> 8B store
                *(f16x4*)(dst + (size_t)((mb >> 11)*16 + (n >> 6))*131072 + (size_t)(n & 63)*2048 + (mb & 2047)) = o;
            } else {
                float* dst = (float*)outp;
                #pragma unroll
                for (int j = 0; j < 4; ++j) {
                    const int m = mb + j;
                    dst[(size_t)m * NDM + n] = acc[rt][ct][j] + bn;
                }
            }
        }
    }
}

// fused QKV projection: grid (8, 32, 3)
__global__ __launch_bounds__(256) void proj_kernel(const f16* __restrict__ xh, const f16* __restrict__ wt,
                                                   const float* __restrict__ bq, const float* __restrict__ bk,
                                                   const float* __restrict__ bv,
                                                   f16* __restrict__ qh, f16* __restrict__ kh, f16* __restrict__ vh)
{
    __shared__ f16 AsS[2*4096];
    __shared__ f16 BsS[2*4096];
    const int z = blockIdx.z;
    const f16* A  = xh + (size_t)z * ((size_t)NM * NDM);
    const f16* Bw = wt + (size_t)z * ((size_t)NDM * NDM);
    if (z == 0)      gemm128<0>(A, Bw, bq, qh, AsS, BsS);
    else if (z == 1) gemm128<1>(A, Bw, bk, kh, AsS, BsS);
    else             gemm128<2>(A, Bw, bv, vh, AsS, BsS);
}

// output projection: grid (8, 32)
__global__ __launch_bounds__(256) void outproj_kernel(const f16* __restrict__ ah, const f16* __restrict__ wto,
                                                      const float* __restrict__ bo, float* __restrict__ out)
{
    __shared__ f16 AsS[2*4096];
    __shared__ f16 BsS[2*4096];
    gemm128<3>(ah, wto, bo, out, AsS, BsS);
}

// ---------------------------------------------------------------------------
// K2: fused attention, 128-q blocks, LDS-shared K/V chunks, P-in-registers.
// Grid: 512 blocks (8 XCD x 4 bh x 16 q-tiles) x 512 thr = 2 blocks/CU, all
// co-resident. Wave w OWNS q-rows qbase+w*16+{0..15}: rowsum needs only 2
// shfl_xor (no barrier, no LDS). K (and V in pass 2) stream through double-
// buffered LDS chunks of 64 k-rows SHARED by all 8 waves: L2 K/V traffic
// drops 8x vs 16-q blocks (2 GB -> 400 MB) -- that traffic was the real
// bottleneck of rounds 3-9.
// Pass 1: QK (A=K-frag from LDS, B=q-frag regs) -> exp2 -> rowsum only.
// Pass 2: recompute QK, nt-store normalized f32 weights straight from regs
// (64B-contiguous per g-group), PV via 16x16x16 MFMA whose B-fragment
// [k=g*4+u][col=q=l15] IS the QK output register layout (no LDS round-trip).
// q pre-scaled by 0.125*log2e in proj -> plain v_exp_f32.
// ---------------------------------------------------------------------------
__global__ __launch_bounds__(512, 4) void attn_kernel(const f16* __restrict__ qh,
                                                      const f16* __restrict__ kh,
                                                      const f16* __restrict__ vt,
                                                      f16* __restrict__ ah,
                                                      float* __restrict__ wout)
{
    __shared__ f16 Ks[2][64][72];   // [buf][k-row][d + 8 pad]  18 KB
    __shared__ f16 Vs[2][64][72];   // [buf][d-row][k + 8 pad]  18 KB

    const int tid  = threadIdx.x;
    const int lane = tid & 63;
    const int wid  = tid >> 6;
    const int l15  = lane & 15;
    const int g    = lane >> 4;

    // XCD swizzle: 4 bh per XCD; all 16 q-tile blocks of a bh on one XCD.
    const int xcd = blockIdx.x & 7;
    const int j   = blockIdx.x >> 3;
    const int bh  = xcd * 4 + (j & 3);
    const int qt  = j >> 2;                 // 0..15
    const int qg  = qt*128 + wid*16 + l15;  // this lane's q row (wave owns 16 rows)

    const f16* kp = kh + (size_t)bh * NS * 64;
    const f16* vp = vt + (size_t)bh * 64 * NS;

    // q fragments (B-operand of QK): col = l15 = q, depth = g*8+e (+32)
    const f16* qp = qh + ((size_t)bh * NS + qg) * 64;
    const f16x8 qf0 = *(const f16x8*)(qp + g*8);
    const f16x8 qf1 = *(const f16x8*)(qp + 32 + g*8);

    // staging coords: thread loads one f16x8; K chunk = 64 k-rows x 64 d,
    // V chunk = 64 d-rows x 64 k (from vt [B,H,D,S])
    const int sr = tid >> 3;            // 0..63
    const int sc = (tid & 7) * 8;       // 0..56
    const f16* kRow = kp + (size_t)sr * 64 + sc;   // + t*4096
    const f16* vRow = vp + (size_t)sr * NS + sc;   // + t*64

    // ---- pass 1: rowsum of exp2 ----
    float rs = 0.f;
    {
        f16x8 kreg = *(const f16x8*)(kRow);
        *(f16x8*)(&Ks[0][sr][sc]) = kreg;
        int buf = 0;
        for (int t = 0; t < 32; ++t) {
            const bool more = (t + 1 < 32);
            if (more) kreg = *(const f16x8*)(kRow + (size_t)(t+1) * 4096);
            __syncthreads();
            #pragma unroll
            for (int fk = 0; fk < 4; ++fk) {
                f16x8 A0 = *(const f16x8*)(&Ks[buf][fk*16 + l15][g*8]);
                f16x8 A1 = *(const f16x8*)(&Ks[buf][fk*16 + l15][32 + g*8]);
                f32x4 a = {0.f,0.f,0.f,0.f};
                a = __builtin_amdgcn_mfma_f32_16x16x32_f16(A0, qf0, a, 0,0,0);
                a = __builtin_amdgcn_mfma_f32_16x16x32_f16(A1, qf1, a, 0,0,0);
                #pragma unroll
                for (int u = 0; u < 4; ++u) rs += __builtin_amdgcn_exp2f(a[u]);
            }
            __syncthreads();
            if (more) *(f16x8*)(&Ks[buf^1][sr][sc]) = kreg;
            buf ^= 1;
        }
    }
    rs += __shfl_xor(rs, 16);
    rs += __shfl_xor(rs, 32);
    const float ri = 1.0f / rs;

    // ---- pass 2: QK again + normalized weights store + PV ----
    f32x4 acc0 = {0.f,0.f,0.f,0.f}, acc1 = acc0, acc2 = acc0, acc3 = acc0;
    float* wr = wout + ((size_t)bh * NS + qg) * NS;   // + t*64 + fk*16 + g*4
    {
        f16x8 kreg = *(const f16x8*)(kRow);
        f16x8 vreg = *(const f16x8*)(vRow);
        *(f16x8*)(&Ks[0][sr][sc]) = kreg;
        *(f16x8*)(&Vs[0][sr][sc]) = vreg;
        int buf = 0;
        for (int t = 0; t < 32; ++t) {
            const bool more = (t + 1 < 32);
            if (more) {
                kreg = *(const f16x8*)(kRow + (size_t)(t+1) * 4096);
                vreg = *(const f16x8*)(vRow + (t+1) * 64);
            }
            __syncthreads();
            #pragma unroll
            for (int fk = 0; fk < 4; ++fk) {
                f16x8 A0 = *(const f16x8*)(&Ks[buf][fk*16 + l15][g*8]);
                f16x8 A1 = *(const f16x8*)(&Ks[buf][fk*16 + l15][32 + g*8]);
                f32x4 a = {0.f,0.f,0.f,0.f};
                a = __builtin_amdgcn_mfma_f32_16x16x32_f16(A0, qf0, a, 0,0,0);
                a = __builtin_amdgcn_mfma_f32_16x16x32_f16(A1, qf1, a, 0,0,0);
                // lane: S[q=l15][k = t*64 + fk*16 + g*4+u]
                f32x4 e; f16x4 p;
                #pragma unroll
                for (int u = 0; u < 4; ++u) {
                    e[u] = __builtin_amdgcn_exp2f(a[u]);
                    p[u] = (f16)e[u];
                }
                // normalized weights straight from registers (nt, fire-and-forget)
                f32x4 w;
                #pragma unroll
                for (int u = 0; u < 4; ++u) w[u] = e[u] * ri;
                __builtin_nontemporal_store(w, (f32x4*)(wr + t*64 + fk*16 + g*4));
                // PV 16x16x16: A = V^T frag [d=dt*16+l15][k=g*4+u], B = p
                f16x4 v0 = *(const f16x4*)(&Vs[buf][ 0 + l15][fk*16 + g*4]);
                f16x4 v1 = *(const f16x4*)(&Vs[buf][16 + l15][fk*16 + g*4]);
                f16x4 v2 = *(const f16x4*)(&Vs[buf][32 + l15][fk*16 + g*4]);
                f16x4 v3 = *(const f16x4*)(&Vs[buf][48 + l15][fk*16 + g*4]);
                acc0 = __builtin_amdgcn_mfma_f32_16x16x16f16(v0, p, acc0, 0,0,0);
                acc1 = __builtin_amdgcn_mfma_f32_16x16x16f16(v1, p, acc1, 0,0,0);
                acc2 = __builtin_amdgcn_mfma_f32_16x16x16f16(v2, p, acc2, 0,0,0);
                acc3 = __builtin_amdgcn_mfma_f32_16x16x16f16(v3, p, acc3, 0,0,0);
            }
            __syncthreads();
            if (more) {
                *(f16x8*)(&Ks[buf^1][sr][sc]) = kreg;
                *(f16x8*)(&Vs[buf^1][sr][sc]) = vreg;
            }
            buf ^= 1;
        }
    }

    // epilogue: lane holds out[d = dt*16 + g*4+u][q = l15]; normalize, 8B stores
    {
        const int bb = bh >> 4, hh = bh & 15;
        f16* arow = ah + ((size_t)(bb*NS + qg)) * NDM + hh*64 + g*4;
        f16x4 o;
        #pragma unroll
        for (int u = 0; u < 4; ++u) o[u] = (f16)(acc0[u] * ri);
        *(f16x4*)(arow) = o;
        #pragma unroll
        for (int u = 0; u < 4; ++u) o[u] = (f16)(acc1[u] * ri);
        *(f16x4*)(arow + 16) = o;
        #pragma unroll
        for (int u = 0; u < 4; ++u) o[u] = (f16)(acc2[u] * ri);
        *(f16x4*)(arow + 32) = o;
        #pragma unroll
        for (int u = 0; u < 4; ++u) o[u] = (f16)(acc3[u] * ri);
        *(f16x4*)(arow + 48) = o;
    }
}

// ---------------------------------------------------------------------------
extern "C" void kernel_launch(void* const* d_in, const int* in_sizes, int n_in,
                              void* d_out, int out_size, void* d_ws, size_t ws_size,
                              hipStream_t stream)
{
    (void)in_sizes; (void)n_in; (void)out_size;
    const float* Q  = (const float*)d_in[0];
    const float* K  = (const float*)d_in[1];
    const float* V  = (const float*)d_in[2];
    const float* Wq = (const float*)d_in[3];
    const float* bq = (const float*)d_in[4];
    const float* Wk = (const float*)d_in[5];
    const float* bk = (const float*)d_in[6];
    const float* Wv = (const float*)d_in[7];
    const float* bv = (const float*)d_in[8];
    const float* Wo = (const float*)d_in[9];
    const float* bo = (const float*)d_in[10];

    if (ws_size < 67108864ull) return;  // need 64 MiB; abort -> stub-like absmax signals this

    f16* ws = (f16*)d_ws;
    f16* Xh = ws;                  // 3 x [4096][1024] f16 (Q,K,V inputs)
    f16* Wt = ws + 12582912;       // 4 x [1024][1024] f16 (W^T: q,k,v,o)
    f16* qh = ws + 16777216;       // [B,H,S,D] f16, pre-scaled by 0.125*log2e
    f16* kh = ws + 20971520;       // [B,H,S,D] f16
    f16* vt = ws + 25165824;       // [B,H,D,S] f16 (transposed)
    f16* ah = ws + 29360128;       // [B,S,DM] f16 (attn concat)
    float* out  = (float*)d_out;
    float* wout = out + 4194304;   // weights region

    cvt_x_kernel  <<<dim3(2048, 3, 1), dim3(256), 0, stream>>>(Q, K, V, Xh);
    transp_w_kernel<<<dim3(16, 16, 4), dim3(256), 0, stream>>>(Wq, Wk, Wv, Wo, Wt);
    proj_kernel   <<<dim3(8, 32, 3),  dim3(256), 0, stream>>>(Xh, Wt, bq, bk, bv, qh, kh, vt);
    attn_kernel   <<<dim3(512),       dim3(512), 0, stream>>>(qh, kh, vt, ah, wout);
    outproj_kernel<<<dim3(8, 32, 1),  dim3(256), 0, stream>>>(ah, Wt + 3*1048576, bo, out);
}